// Round 4
// baseline (853.115 us; speedup 1.0000x reference)
//
#include <hip/hip_runtime.h>
#include <hip/hip_bf16.h>
#include <math.h>

typedef __hip_bfloat16 bf16;
using v8bf = __attribute__((ext_vector_type(8))) __bf16;
using v4f  = __attribute__((ext_vector_type(4))) float;

#define T_SEQ 2048
#define DMODEL 2048
#define NHEADS 16
#define HDIM 128
#define RDIM 64

__device__ __forceinline__ short f2bfbits(float f) {
  bf16 h = __float2bfloat16(f);
  short s;
  __builtin_memcpy(&s, &h, 2);
  return s;
}

// async global->LDS, 16B per lane; LDS dest is wave-uniform base + lane*16
typedef const __attribute__((address_space(1))) unsigned gu32;
typedef __attribute__((address_space(3))) unsigned lu32;
__device__ __forceinline__ void gl_lds16(const void* g, void* l) {
  __builtin_amdgcn_global_load_lds((gu32*)g, (lu32*)l, 16, 0, 0);
}

// ---------------- dtype detection: are inputs f32 or bf16? ----------------
__global__ void detect_k(const unsigned* __restrict__ x, int* __restrict__ flag) {
  __shared__ int cnt;
  if (threadIdx.x == 0) cnt = 0;
  __syncthreads();
  int c = 0;
#pragma unroll
  for (int i = 0; i < 4; i++) {
    unsigned w = x[threadIdx.x * 4 + i];
    unsigned e = (w >> 7) & 0xFFu;
    if (e < 97u || e > 157u) c++;
  }
  atomicAdd(&cnt, c);
  __syncthreads();
  if (threadIdx.x == 0) flag[0] = (cnt > 256) ? 1 : 0;  // 1 = f32 inputs
}

// ---------------- canonicalize: any-dtype -> bf16 / f32 ----------------
__global__ __launch_bounds__(256) void conv_bf_k(const void* __restrict__ src,
                                                 bf16* __restrict__ dst,
                                                 const int* __restrict__ flag, int n) {
  int i = blockIdx.x * 256 + threadIdx.x;
  if (i >= n) return;
  if (*flag) dst[i] = __float2bfloat16(((const float*)src)[i]);
  else       dst[i] = ((const bf16*)src)[i];
}

__global__ __launch_bounds__(256) void conv_f_k(const void* __restrict__ src,
                                                float* __restrict__ dst,
                                                const int* __restrict__ flag, int n) {
  int i = blockIdx.x * 256 + threadIdx.x;
  if (i >= n) return;
  if (*flag) dst[i] = ((const float*)src)[i];
  else       dst[i] = __bfloat162float(((const bf16*)src)[i]);
}

// ---------------- weight transpose + canonicalize ----------------
__global__ __launch_bounds__(256) void transpose_any(const void* __restrict__ src,
                                                     bf16* __restrict__ dst,
                                                     int rows, int cols,
                                                     const int* __restrict__ flag) {
  __shared__ bf16 tile[32][33];
  int bx = blockIdx.x * 32, by = blockIdx.y * 32;
  int tx = threadIdx.x & 31, ty = threadIdx.x >> 5;
  bool isf = (*flag != 0);
#pragma unroll
  for (int i = 0; i < 32; i += 8) {
    size_t idx = (size_t)(by + ty + i) * cols + bx + tx;
    tile[ty + i][tx] = isf ? __float2bfloat16(((const float*)src)[idx])
                           : ((const bf16*)src)[idx];
  }
  __syncthreads();
#pragma unroll
  for (int i = 0; i < 32; i += 8)
    dst[(size_t)(bx + ty + i) * rows + by + tx] = tile[tx][ty + i];
}

// ---------------- bf16 transpose (for V^T) ----------------
__global__ __launch_bounds__(256) void transpose_bf(const bf16* __restrict__ src,
                                                    bf16* __restrict__ dst,
                                                    int rows, int cols) {
  __shared__ bf16 tile[32][33];
  int bx = blockIdx.x * 32, by = blockIdx.y * 32;
  int tx = threadIdx.x & 31, ty = threadIdx.x >> 5;
#pragma unroll
  for (int i = 0; i < 32; i += 8)
    tile[ty + i][tx] = src[(size_t)(by + ty + i) * cols + bx + tx];
  __syncthreads();
#pragma unroll
  for (int i = 0; i < 32; i += 8)
    dst[(size_t)(bx + ty + i) * rows + by + tx] = tile[tx][ty + i];
}

// ---------------- TN GEMM: C[M,N] = A[M,K] * BT[N,K]^T ----------------
// 128x128 tile, BK=32. Staging via global_load_lds (16B/lane, async DMA).
// LDS granule layout G(row,kq) = (row>>3)*32 + kq*8 + (row&7):
//  - within a 1KB region (16 rows), granule index == lane index  -> legal DMA dest
//  - frag-read bank group == row&7 -> 2-way conflict only (free)
__global__ __launch_bounds__(256) void gemm_tn(const bf16* __restrict__ A,
                                               const bf16* __restrict__ BT,
                                               float* __restrict__ Cf,
                                               bf16* __restrict__ Cb,
                                               int M, int N, int K) {
  __shared__ __align__(16) short lsa[128 * 32];
  __shared__ __align__(16) short lsb[128 * 32];
  const int m0 = blockIdx.y * 128, n0 = blockIdx.x * 128;
  const int tid = threadIdx.x;
  const int w = tid >> 6, lane = tid & 63, quad = lane >> 4, l16 = lane & 15;
  const int wm = (w >> 1) * 64, wn = (w & 1) * 64;
  // per-lane staging source decode (region-relative)
  const int srow = ((lane >> 5) & 1) * 8 + (lane & 7);  // row within 16-row region
  const int skq  = (lane >> 3) & 3;                     // 8-elem k-granule
  const int r0 = w * 2, r1 = w * 2 + 1;                 // this wave's regions
  const bf16* Ab0 = A  + (size_t)(m0 + r0 * 16 + srow) * K + skq * 8;
  const bf16* Ab1 = A  + (size_t)(m0 + r1 * 16 + srow) * K + skq * 8;
  const bf16* Bb0 = BT + (size_t)(n0 + r0 * 16 + srow) * K + skq * 8;
  const bf16* Bb1 = BT + (size_t)(n0 + r1 * 16 + srow) * K + skq * 8;
  short* la0 = &lsa[r0 * 512];
  short* la1 = &lsa[r1 * 512];
  short* lb0 = &lsb[r0 * 512];
  short* lb1 = &lsb[r1 * 512];

  v4f acc[4][4];
#pragma unroll
  for (int i = 0; i < 4; i++)
#pragma unroll
    for (int j = 0; j < 4; j++) acc[i][j] = (v4f){0.f, 0.f, 0.f, 0.f};

  for (int kb = 0; kb < K; kb += 32) {
    __syncthreads();  // WAR: prior frag reads done before DMA overwrites
    gl_lds16(Ab0 + kb, la0);
    gl_lds16(Ab1 + kb, la1);
    gl_lds16(Bb0 + kb, lb0);
    gl_lds16(Bb1 + kb, lb1);
    __syncthreads();  // drains vmcnt(0): DMA complete for all waves

    v8bf af[4], bfr[4];
#pragma unroll
    for (int i = 0; i < 4; i++) {
      int row = wm + i * 16 + l16;
      af[i] = *reinterpret_cast<const v8bf*>(
          &lsa[((row >> 3) << 8) + (quad << 6) + ((row & 7) << 3)]);
    }
#pragma unroll
    for (int j = 0; j < 4; j++) {
      int row = wn + j * 16 + l16;
      bfr[j] = *reinterpret_cast<const v8bf*>(
          &lsb[((row >> 3) << 8) + (quad << 6) + ((row & 7) << 3)]);
    }
#pragma unroll
    for (int i = 0; i < 4; i++)
#pragma unroll
      for (int j = 0; j < 4; j++)
        acc[i][j] = __builtin_amdgcn_mfma_f32_16x16x32_bf16(af[i], bfr[j], acc[i][j], 0, 0, 0);
  }
#pragma unroll
  for (int i = 0; i < 4; i++)
#pragma unroll
    for (int j = 0; j < 4; j++)
#pragma unroll
      for (int r = 0; r < 4; r++) {
        int row = m0 + wm + i * 16 + quad * 4 + r;
        int col = n0 + wn + j * 16 + l16;
        float vv = acc[i][j][r];
        if (Cf) Cf[(size_t)row * N + col] = vv;
        else    Cb[(size_t)row * N + col] = __float2bfloat16(vv);
      }
}

// ---------------- RMS norm: fp32 raw -> bf16 ----------------
__global__ __launch_bounds__(256) void rmsnorm_k(const float* __restrict__ raw,
                                                 const bf16* __restrict__ w,
                                                 bf16* __restrict__ o, int C) {
  int row = blockIdx.x, tid = threadIdx.x;
  const float* r = raw + (size_t)row * C;
  float s = 0.f;
  for (int i = tid; i < C; i += 256) { float v = r[i]; s += v * v; }
#pragma unroll
  for (int m = 32; m; m >>= 1) s += __shfl_xor(s, m);
  __shared__ float red[4];
  if ((tid & 63) == 0) red[tid >> 6] = s;
  __syncthreads();
  float tot = red[0] + red[1] + red[2] + red[3];
  float rs = rsqrtf(tot / (float)C + 1e-6f);
  for (int i = tid; i < C; i += 256)
    o[(size_t)row * C + i] = __float2bfloat16(r[i] * rs * __bfloat162float(w[i]));
}

// ---------------- gate: alpha = sigmoid(x . Wg + bg) ----------------
__global__ __launch_bounds__(256) void gate_k(const bf16* __restrict__ x,
                                              const bf16* __restrict__ wg,
                                              const bf16* __restrict__ bg,
                                              float* __restrict__ af) {
  int row = blockIdx.x, tid = threadIdx.x;
  const bf16* xr = x + (size_t)row * DMODEL;
  float s = 0.f;
  for (int i = tid; i < DMODEL; i += 256)
    s += __bfloat162float(xr[i]) * __bfloat162float(wg[i]);
#pragma unroll
  for (int m = 32; m; m >>= 1) s += __shfl_xor(s, m);
  __shared__ float red[4];
  if ((tid & 63) == 0) red[tid >> 6] = s;
  __syncthreads();
  if (tid == 0) {
    float tot = red[0] + red[1] + red[2] + red[3] + __bfloat162float(bg[0]);
    af[row] = 1.f / (1.f + expf(-tot));
  }
}

// ---------------- EPE rope, in-place on q_r and k_r ----------------
__global__ __launch_bounds__(256) void rope_k(bf16* __restrict__ qr,
                                              bf16* __restrict__ kr,
                                              const float* __restrict__ unc) {
  int idx = blockIdx.x * 256 + threadIdx.x;
  int j = idx & 31, h = (idx >> 5) & 15, bt = idx >> 9;
  int t = bt & (T_SEQ - 1);
  float u = unc[bt];
  u = fminf(fmaxf(u, 0.f), 1.f);
  float scale = 0.5f + 1.5f * u;
  float theta = expf(-(float)j * (1.f / 32.f) * logf(500000.f));
  float f = (float)t * theta * scale;
  float c = cosf(f), s = sinf(f);
  size_t base = (size_t)bt * (NHEADS * RDIM) + h * RDIM + j;
  {
    float x1 = __bfloat162float(qr[base]), x2 = __bfloat162float(qr[base + 32]);
    qr[base]      = __float2bfloat16(x1 * c - x2 * s);
    qr[base + 32] = __float2bfloat16(x2 * c + x1 * s);
  }
  {
    float x1 = __bfloat162float(kr[base]), x2 = __bfloat162float(kr[base + 32]);
    kr[base]      = __float2bfloat16(x1 * c - x2 * s);
    kr[base + 32] = __float2bfloat16(x2 * c + x1 * s);
  }
}

// ---------------- flash attention, fixed-max softmax ----------------
// 512 threads = 8 waves, Q-tile 128 (wave w owns rows w*16..w*16+15),
// K-tile 64. K/V staging amortized over 2x the MFMA vs the 64-query version.
template <int IS_AR>
__global__ __launch_bounds__(512) void attn_k(const bf16* __restrict__ qc,
                                              const bf16* __restrict__ qr,
                                              const bf16* __restrict__ kc,
                                              const bf16* __restrict__ kr,
                                              const bf16* __restrict__ vt,
                                              const bf16* __restrict__ ob,
                                              const float* __restrict__ alphaF,
                                              bf16* __restrict__ out) {
  constexpr int LDK = 200;  // rows 400B -> 2-way banks (free)
  constexpr int LDV = 72;
  constexpr int LDP = 72;
  __shared__ __align__(16) short lk[64 * LDK];
  __shared__ __align__(16) short lvt[128 * LDV];
  __shared__ __align__(16) short lp[8 * 16 * LDP];

  const int b = blockIdx.z, h = blockIdx.y, qt = blockIdx.x;
  const int qs = qt * 128;
  const int tid = threadIdx.x;
  const int w = tid >> 6, lane = tid & 63, quad = lane >> 4, l16 = lane & 15;
  const int q0 = qs + w * 16;

  v8bf qf[6];
  {
    int qrow = q0 + l16;
    size_t cbase = ((size_t)b * T_SEQ + qrow) * DMODEL + h * HDIM;
#pragma unroll
    for (int s_ = 0; s_ < 4; s_++)
      qf[s_] = *reinterpret_cast<const v8bf*>(qc + cbase + s_ * 32 + quad * 8);
    size_t rbase = ((size_t)b * T_SEQ + qrow) * (NHEADS * RDIM) + h * RDIM;
#pragma unroll
    for (int s_ = 0; s_ < 2; s_++)
      qf[4 + s_] = *reinterpret_cast<const v8bf*>(qr + rbase + s_ * 32 + quad * 8);
  }

  float l_lane[4] = {0.f, 0.f, 0.f, 0.f};
  v4f oacc[8];
#pragma unroll
  for (int i = 0; i < 8; i++) oacc[i] = (v4f){0.f, 0.f, 0.f, 0.f};

  int klo = 0, khi = T_SEQ;
  if (IS_AR) {
    int c = qs >> 8;                      // chunk index (CHUNK=256); uniform for 128-tile
    klo = (c > 0) ? (c * 256 - 256) : 0;  // window lower bound
    khi = qs + 128;                       // causal upper bound for this tile
  }
  const float sc = 0.07216878364870323f;  // 1/sqrt(192)

  short* pw = &lp[w * 16 * LDP];  // wave-private P region

  for (int kb = klo; kb < khi; kb += 64) {
    __syncthreads();  // WAR on lk/lvt
    // stage K tile: 64 keys x 192 (kc | kr) = 1536 chunks over 512 threads
#pragma unroll
    for (int i = 0; i < 3; i++) {
      int c = i * 512 + tid;
      int row = c / 24, dg = c % 24;
      int key = kb + row;
      const bf16* src;
      if (dg < 16) src = kc + ((size_t)b * T_SEQ + key) * DMODEL + h * HDIM + dg * 8;
      else         src = kr + ((size_t)b * T_SEQ + key) * (NHEADS * RDIM) + h * RDIM + (dg - 16) * 8;
      *reinterpret_cast<v8bf*>(&lk[row * LDK + dg * 8]) = *reinterpret_cast<const v8bf*>(src);
    }
    // stage V^T tile: 1024 chunks (128 d x 8 key-groups) over 512 threads
#pragma unroll
    for (int i = 0; i < 2; i++) {
      int c = i * 512 + tid;
      int d = c >> 3, kg = c & 7;
      *reinterpret_cast<v8bf*>(&lvt[d * LDV + kg * 8]) =
          *reinterpret_cast<const v8bf*>(vt + (size_t)(h * HDIM + d) * (2 * T_SEQ) + b * T_SEQ + kb + kg * 8);
    }
    __syncthreads();

    const bool wactive = !IS_AR || (kb <= q0 + 15);
    if (wactive) {
      float pnew[4][4];
#pragma unroll
      for (int j = 0; j < 4; j++) {
        const bool jact = !IS_AR || (kb + j * 16 <= q0 + 15);
        if (jact) {
          v4f a = (v4f){0.f, 0.f, 0.f, 0.f};
#pragma unroll
          for (int s_ = 0; s_ < 6; s_++) {
            v8bf kf = *reinterpret_cast<const v8bf*>(&lk[(j * 16 + l16) * LDK + s_ * 32 + quad * 8]);
            a = __builtin_amdgcn_mfma_f32_16x16x32_bf16(qf[s_], kf, a, 0, 0, 0);
          }
#pragma unroll
          for (int r = 0; r < 4; r++) {
            float p = __expf(a[r] * sc);
            if (IS_AR) {
              int k = kb + j * 16 + l16;
              int q = q0 + quad * 4 + r;
              p = (k <= q) ? p : 0.f;
            }
            pnew[r][j] = p;
            l_lane[r] += p;
          }
        } else {
#pragma unroll
          for (int r = 0; r < 4; r++) pnew[r][j] = 0.f;
        }
      }
      // P: C-layout -> wave-private LDS -> A-layout
#pragma unroll
      for (int r = 0; r < 4; r++) {
        int prow = quad * 4 + r;
#pragma unroll
        for (int j = 0; j < 4; j++)
          pw[prow * LDP + j * 16 + l16] = f2bfbits(pnew[r][j]);
      }
      asm volatile("s_waitcnt lgkmcnt(0)" ::: "memory");
      v8bf pf[2];
#pragma unroll
      for (int st = 0; st < 2; st++)
        pf[st] = *reinterpret_cast<const v8bf*>(&pw[l16 * LDP + st * 32 + quad * 8]);
#pragma unroll
      for (int nd = 0; nd < 8; nd++) {
#pragma unroll
        for (int st = 0; st < 2; st++) {
          v8bf vf = *reinterpret_cast<const v8bf*>(&lvt[(nd * 16 + l16) * LDV + st * 32 + quad * 8]);
          oacc[nd] = __builtin_amdgcn_mfma_f32_16x16x32_bf16(pf[st], vf, oacc[nd], 0, 0, 0);
        }
      }
    }
  }

  // epilogue: reduce l across the 16 lanes of each quad-group, then write
#pragma unroll
  for (int r = 0; r < 4; r++) {
    float l = l_lane[r];
#pragma unroll
    for (int m = 1; m < 16; m <<= 1) l += __shfl_xor(l, m);
    float inv = 1.f / l;
    int q = q0 + quad * 4 + r;
    size_t base = ((size_t)b * T_SEQ + q) * DMODEL + h * HDIM;
    if (IS_AR) {
      float a = alphaF[b * T_SEQ + q];
#pragma unroll
      for (int nd = 0; nd < 8; nd++) {
        float vb = __bfloat162float(ob[base + nd * 16 + l16]);
        out[base + nd * 16 + l16] = __float2bfloat16(a * vb + (1.f - a) * (oacc[nd][r] * inv));
      }
    } else {
#pragma unroll
      for (int nd = 0; nd < 8; nd++)
        out[base + nd * 16 + l16] = __float2bfloat16(oacc[nd][r] * inv);
    }
  }
}

// ---------------- emit: fp32 staging -> d_out in detected dtype ----------------
__global__ __launch_bounds__(256) void emit_k(const float* __restrict__ outf,
                                              const float* __restrict__ alphaF,
                                              void* __restrict__ dout,
                                              const int* __restrict__ flag) {
  int idx = blockIdx.x * 256 + threadIdx.x;
  float vv = (idx < 8388608) ? outf[idx] : alphaF[idx - 8388608];
  if (*flag) ((float*)dout)[idx] = vv;
  else       ((bf16*)dout)[idx] = __float2bfloat16(vv);
}

extern "C" void kernel_launch(void* const* d_in, const int* in_sizes, int n_in,
                              void* d_out, int out_size, void* d_ws, size_t ws_size,
                              hipStream_t stream) {
  const void* x_raw    = d_in[0];
  const void* unc_raw  = d_in[1];
  const void* Wqd_raw  = d_in[2];
  const void* qnw_raw  = d_in[3];
  const void* Wqu_raw  = d_in[4];
  const void* Wqr_raw  = d_in[5];
  const void* Wkvd_raw = d_in[6];
  const void* kvnw_raw = d_in[7];
  const void* Wku_raw  = d_in[8];
  const void* Wvu_raw  = d_in[9];
  const void* Wkr_raw  = d_in[10];
  const void* Wo_raw   = d_in[11];
  const void* Wg_raw   = d_in[12];
  const void* bg_raw   = d_in[13];

  char* ws = (char*)d_ws;
  size_t off = 0;
  auto alloc = [&](size_t bytes) -> void* {
    char* p = ws + off;
    off += (bytes + 255) & ~(size_t)255;
    return p;
  };
  int*  flag   = (int*)alloc(256);
  bf16* xc     = (bf16*)alloc((size_t)4096 * 2048 * 2);
  float* uncf  = (float*)alloc((size_t)4096 * 4);
  bf16* qnw    = (bf16*)alloc(1536 * 2);
  bf16* kvnw   = (bf16*)alloc(512 * 2);
  bf16* wgc    = (bf16*)alloc(2048 * 2);
  bf16* bgc    = (bf16*)alloc(256);
  bf16* WqdT   = (bf16*)alloc((size_t)2048 * 1536 * 2);
  bf16* WquT   = (bf16*)alloc((size_t)1536 * 2048 * 2);
  bf16* WqrT   = (bf16*)alloc((size_t)1536 * 1024 * 2);
  bf16* WkvdT  = (bf16*)alloc((size_t)2048 * 512 * 2);
  bf16* WkuT   = (bf16*)alloc((size_t)512 * 2048 * 2);
  bf16* WvuT   = (bf16*)alloc((size_t)512 * 2048 * 2);
  bf16* WkrT   = (bf16*)alloc((size_t)2048 * 1024 * 2);
  bf16* WoT    = (bf16*)alloc((size_t)2048 * 2048 * 2);
  float* q_raw = (float*)alloc((size_t)4096 * 1536 * 4);
  float* kv_raw= (float*)alloc((size_t)4096 * 512 * 4);
  bf16* q_lat  = (bf16*)alloc((size_t)4096 * 1536 * 2);
  bf16* kv_lat = (bf16*)alloc((size_t)4096 * 512 * 2);
  bf16* q_c    = (bf16*)alloc((size_t)4096 * 2048 * 2);
  bf16* q_r    = (bf16*)alloc((size_t)4096 * 1024 * 2);
  bf16* k_c    = (bf16*)alloc((size_t)4096 * 2048 * 2);
  bf16* k_r    = (bf16*)alloc((size_t)4096 * 1024 * 2);
  bf16* vbuf   = (bf16*)alloc((size_t)4096 * 2048 * 2);
  bf16* out_b  = (bf16*)alloc((size_t)4096 * 2048 * 2);
  bf16* vT     = (bf16*)alloc((size_t)4096 * 2048 * 2);
  float* alphaF= (float*)alloc((size_t)4096 * 4);
  float* out_f = q_raw;   // q_raw+kv_raw contiguous, dead after rmsnorm
  bf16* merged = q_c;     // q_c dead after attention

  detect_k<<<1, 256, 0, stream>>>((const unsigned*)x_raw, flag);

  conv_bf_k<<<32768, 256, 0, stream>>>(x_raw, xc, flag, 4096 * 2048);
  conv_bf_k<<<6, 256, 0, stream>>>(qnw_raw, qnw, flag, 1536);
  conv_bf_k<<<2, 256, 0, stream>>>(kvnw_raw, kvnw, flag, 512);
  conv_bf_k<<<8, 256, 0, stream>>>(Wg_raw, wgc, flag, 2048);
  conv_bf_k<<<1, 256, 0, stream>>>(bg_raw, bgc, flag, 1);
  conv_f_k<<<16, 256, 0, stream>>>(unc_raw, uncf, flag, 4096);

  auto lt = [&](const void* s, bf16* d, int r, int c) {
    transpose_any<<<dim3(c / 32, r / 32), 256, 0, stream>>>(s, d, r, c, flag);
  };
  lt(Wqd_raw, WqdT, 2048, 1536);
  lt(Wqu_raw, WquT, 1536, 2048);
  lt(Wqr_raw, WqrT, 1536, 1024);
  lt(Wkvd_raw, WkvdT, 2048, 512);
  lt(Wku_raw, WkuT, 512, 2048);
  lt(Wvu_raw, WvuT, 512, 2048);
  lt(Wkr_raw, WkrT, 2048, 1024);
  lt(Wo_raw, WoT, 2048, 2048);

  auto gemmf = [&](const bf16* A, const bf16* BT, float* C, int M, int N, int K) {
    gemm_tn<<<dim3(N / 128, M / 128), 256, 0, stream>>>(A, BT, C, nullptr, M, N, K);
  };
  auto gemmb = [&](const bf16* A, const bf16* BT, bf16* C, int M, int N, int K) {
    gemm_tn<<<dim3(N / 128, M / 128), 256, 0, stream>>>(A, BT, nullptr, C, M, N, K);
  };

  gemmf(xc, WqdT, q_raw, 4096, 1536, 2048);
  gemmf(xc, WkvdT, kv_raw, 4096, 512, 2048);
  rmsnorm_k<<<4096, 256, 0, stream>>>(q_raw, qnw, q_lat, 1536);
  rmsnorm_k<<<4096, 256, 0, stream>>>(kv_raw, kvnw, kv_lat, 512);

  gemmb(q_lat, WquT, q_c, 4096, 2048, 1536);
  gemmb(q_lat, WqrT, q_r, 4096, 1024, 1536);
  gemmb(kv_lat, WkuT, k_c, 4096, 2048, 512);
  gemmb(kv_lat, WvuT, vbuf, 4096, 2048, 512);
  gemmb(xc, WkrT, k_r, 4096, 1024, 2048);

  // V^T for attention staging: vT[col=h*128+d][row=b*2048+t]
  transpose_bf<<<dim3(64, 128), 256, 0, stream>>>(vbuf, vT, 4096, 2048);

  rope_k<<<8192, 256, 0, stream>>>(q_r, k_r, uncf);
  gate_k<<<4096, 256, 0, stream>>>(xc, wgc, bgc, alphaF);

  attn_k<0><<<dim3(16, 16, 2), 512, 0, stream>>>(q_c, q_r, k_c, k_r, vT, nullptr, nullptr, out_b);
  attn_k<1><<<dim3(16, 16, 2), 512, 0, stream>>>(q_c, q_r, k_c, k_r, vT, out_b, alphaF, merged);

  gemmf(merged, WoT, out_f, 4096, 2048, 2048);
  emit_k<<<32784, 256, 0, stream>>>(out_f, alphaF, d_out, flag);

  (void)in_sizes; (void)n_in; (void)out_size; (void)ws_size;
}

// Round 5
// 740.049 us; speedup vs baseline: 1.1528x; 1.1528x over previous
//
#include <hip/hip_runtime.h>
#include <hip/hip_bf16.h>
#include <math.h>

typedef __hip_bfloat16 bf16;
using v8bf = __attribute__((ext_vector_type(8))) __bf16;
using v4f  = __attribute__((ext_vector_type(4))) float;

#define T_SEQ 2048
#define DMODEL 2048
#define NHEADS 16
#define HDIM 128
#define RDIM 64

__device__ __forceinline__ short f2bfbits(float f) {
  bf16 h = __float2bfloat16(f);
  short s;
  __builtin_memcpy(&s, &h, 2);
  return s;
}

// async global->LDS, 16B per lane; LDS dest is wave-uniform base + lane*16
typedef const __attribute__((address_space(1))) unsigned gu32;
typedef __attribute__((address_space(3))) unsigned lu32;
__device__ __forceinline__ void gl_lds16(const void* g, void* l) {
  __builtin_amdgcn_global_load_lds((gu32*)g, (lu32*)l, 16, 0, 0);
}

// ---------------- dtype detection: are inputs f32 or bf16? ----------------
__global__ void detect_k(const unsigned* __restrict__ x, int* __restrict__ flag) {
  __shared__ int cnt;
  if (threadIdx.x == 0) cnt = 0;
  __syncthreads();
  int c = 0;
#pragma unroll
  for (int i = 0; i < 4; i++) {
    unsigned w = x[threadIdx.x * 4 + i];
    unsigned e = (w >> 7) & 0xFFu;
    if (e < 97u || e > 157u) c++;
  }
  atomicAdd(&cnt, c);
  __syncthreads();
  if (threadIdx.x == 0) flag[0] = (cnt > 256) ? 1 : 0;  // 1 = f32 inputs
}

// ---------------- canonicalize big x ----------------
__global__ __launch_bounds__(256) void conv_bf_k(const void* __restrict__ src,
                                                 bf16* __restrict__ dst,
                                                 const int* __restrict__ flag, int n) {
  int i = blockIdx.x * 256 + threadIdx.x;
  if (i >= n) return;
  if (*flag) dst[i] = __float2bfloat16(((const float*)src)[i]);
  else       dst[i] = ((const bf16*)src)[i];
}

// ---------------- fused tiny-input canonicalize ----------------
__global__ __launch_bounds__(256) void conv_small(const void* qnw_raw, const void* kvnw_raw,
                                                  const void* wg_raw, const void* bg_raw,
                                                  const void* unc_raw,
                                                  bf16* qnw, bf16* kvnw, bf16* wgc, bf16* bgc,
                                                  float* uncf, const int* flag) {
  int i = blockIdx.x * 256 + threadIdx.x;
  bool isf = (*flag != 0);
  if (i < 1536) qnw[i] = isf ? __float2bfloat16(((const float*)qnw_raw)[i]) : ((const bf16*)qnw_raw)[i];
  else if (i < 2048) { int j = i - 1536; kvnw[j] = isf ? __float2bfloat16(((const float*)kvnw_raw)[j]) : ((const bf16*)kvnw_raw)[j]; }
  else if (i < 4096) { int j = i - 2048; wgc[j] = isf ? __float2bfloat16(((const float*)wg_raw)[j]) : ((const bf16*)wg_raw)[j]; }
  else if (i < 4097) bgc[0] = isf ? __float2bfloat16(((const float*)bg_raw)[0]) : ((const bf16*)bg_raw)[0];
  else if (i < 8193) { int j = i - 4097; uncf[j] = isf ? ((const float*)unc_raw)[j] : __bfloat162float(((const bf16*)unc_raw)[j]); }
}

// ---------------- weight transpose + canonicalize ----------------
__global__ __launch_bounds__(256) void transpose_any(const void* __restrict__ src,
                                                     bf16* __restrict__ dst,
                                                     int rows, int cols,
                                                     const int* __restrict__ flag) {
  __shared__ bf16 tile[32][33];
  int bx = blockIdx.x * 32, by = blockIdx.y * 32;
  int tx = threadIdx.x & 31, ty = threadIdx.x >> 5;
  bool isf = (*flag != 0);
#pragma unroll
  for (int i = 0; i < 32; i += 8) {
    size_t idx = (size_t)(by + ty + i) * cols + bx + tx;
    tile[ty + i][tx] = isf ? __float2bfloat16(((const float*)src)[idx])
                           : ((const bf16*)src)[idx];
  }
  __syncthreads();
#pragma unroll
  for (int i = 0; i < 32; i += 8)
    dst[(size_t)(bx + ty + i) * rows + by + tx] = tile[tx][ty + i];
}

// ---------------- strided bf16 transpose (for V^T out of fused kcv) ----------------
__global__ __launch_bounds__(256) void transpose_str(const bf16* __restrict__ src,
                                                     bf16* __restrict__ dst,
                                                     int srcStride, int dstStride) {
  __shared__ bf16 tile[32][33];
  int bx = blockIdx.x * 32, by = blockIdx.y * 32;  // bx: col, by: row
  int tx = threadIdx.x & 31, ty = threadIdx.x >> 5;
#pragma unroll
  for (int i = 0; i < 32; i += 8)
    tile[ty + i][tx] = src[(size_t)(by + ty + i) * srcStride + bx + tx];
  __syncthreads();
#pragma unroll
  for (int i = 0; i < 32; i += 8)
    dst[(size_t)(bx + ty + i) * dstStride + by + tx] = tile[tx][ty + i];
}

// ---------------- TN GEMM: C[M,N] = A[M,K] * BT[N,K]^T ----------------
// 128x128 tile, BK=32. Staging via global_load_lds (16B/lane, async DMA).
__global__ __launch_bounds__(256) void gemm_tn(const bf16* __restrict__ A,
                                               const bf16* __restrict__ BT,
                                               float* __restrict__ Cf,
                                               bf16* __restrict__ Cb,
                                               int M, int N, int K) {
  __shared__ __align__(16) short lsa[128 * 32];
  __shared__ __align__(16) short lsb[128 * 32];
  const int m0 = blockIdx.y * 128, n0 = blockIdx.x * 128;
  const int tid = threadIdx.x;
  const int w = tid >> 6, lane = tid & 63, quad = lane >> 4, l16 = lane & 15;
  const int wm = (w >> 1) * 64, wn = (w & 1) * 64;
  const int srow = ((lane >> 5) & 1) * 8 + (lane & 7);
  const int skq  = (lane >> 3) & 3;
  const int r0 = w * 2, r1 = w * 2 + 1;
  const bf16* Ab0 = A  + (size_t)(m0 + r0 * 16 + srow) * K + skq * 8;
  const bf16* Ab1 = A  + (size_t)(m0 + r1 * 16 + srow) * K + skq * 8;
  const bf16* Bb0 = BT + (size_t)(n0 + r0 * 16 + srow) * K + skq * 8;
  const bf16* Bb1 = BT + (size_t)(n0 + r1 * 16 + srow) * K + skq * 8;
  short* la0 = &lsa[r0 * 512];
  short* la1 = &lsa[r1 * 512];
  short* lb0 = &lsb[r0 * 512];
  short* lb1 = &lsb[r1 * 512];

  v4f acc[4][4];
#pragma unroll
  for (int i = 0; i < 4; i++)
#pragma unroll
    for (int j = 0; j < 4; j++) acc[i][j] = (v4f){0.f, 0.f, 0.f, 0.f};

  for (int kb = 0; kb < K; kb += 32) {
    __syncthreads();
    gl_lds16(Ab0 + kb, la0);
    gl_lds16(Ab1 + kb, la1);
    gl_lds16(Bb0 + kb, lb0);
    gl_lds16(Bb1 + kb, lb1);
    __syncthreads();

    v8bf af[4], bfr[4];
#pragma unroll
    for (int i = 0; i < 4; i++) {
      int row = wm + i * 16 + l16;
      af[i] = *reinterpret_cast<const v8bf*>(
          &lsa[((row >> 3) << 8) + (quad << 6) + ((row & 7) << 3)]);
    }
#pragma unroll
    for (int j = 0; j < 4; j++) {
      int row = wn + j * 16 + l16;
      bfr[j] = *reinterpret_cast<const v8bf*>(
          &lsb[((row >> 3) << 8) + (quad << 6) + ((row & 7) << 3)]);
    }
#pragma unroll
    for (int i = 0; i < 4; i++)
#pragma unroll
      for (int j = 0; j < 4; j++)
        acc[i][j] = __builtin_amdgcn_mfma_f32_16x16x32_bf16(af[i], bfr[j], acc[i][j], 0, 0, 0);
  }
#pragma unroll
  for (int i = 0; i < 4; i++)
#pragma unroll
    for (int j = 0; j < 4; j++)
#pragma unroll
      for (int r = 0; r < 4; r++) {
        int row = m0 + wm + i * 16 + quad * 4 + r;
        int col = n0 + wn + j * 16 + l16;
        float vv = acc[i][j][r];
        if (Cf) Cf[(size_t)row * N + col] = vv;
        else    Cb[(size_t)row * N + col] = __float2bfloat16(vv);
      }
}

// ---------------- RMS norm: bf16 strided raw -> bf16 dense ----------------
__global__ __launch_bounds__(256) void rmsnorm_k(const bf16* __restrict__ raw,
                                                 int stride, int off,
                                                 const bf16* __restrict__ w,
                                                 bf16* __restrict__ o, int C) {
  int row = blockIdx.x, tid = threadIdx.x;
  const bf16* r = raw + (size_t)row * stride + off;
  float s = 0.f;
  for (int i = tid; i < C; i += 256) { float v = __bfloat162float(r[i]); s += v * v; }
#pragma unroll
  for (int m = 32; m; m >>= 1) s += __shfl_xor(s, m);
  __shared__ float red[4];
  if ((tid & 63) == 0) red[tid >> 6] = s;
  __syncthreads();
  float tot = red[0] + red[1] + red[2] + red[3];
  float rs = rsqrtf(tot / (float)C + 1e-6f);
  for (int i = tid; i < C; i += 256)
    o[(size_t)row * C + i] = __float2bfloat16(__bfloat162float(r[i]) * rs * __bfloat162float(w[i]));
}

// ---------------- gate: alpha = sigmoid(x . Wg + bg) ----------------
__global__ __launch_bounds__(256) void gate_k(const bf16* __restrict__ x,
                                              const bf16* __restrict__ wg,
                                              const bf16* __restrict__ bg,
                                              float* __restrict__ af) {
  int row = blockIdx.x, tid = threadIdx.x;
  const bf16* xr = x + (size_t)row * DMODEL;
  float s = 0.f;
  for (int i = tid; i < DMODEL; i += 256)
    s += __bfloat162float(xr[i]) * __bfloat162float(wg[i]);
#pragma unroll
  for (int m = 32; m; m >>= 1) s += __shfl_xor(s, m);
  __shared__ float red[4];
  if ((tid & 63) == 0) red[tid >> 6] = s;
  __syncthreads();
  if (tid == 0) {
    float tot = red[0] + red[1] + red[2] + red[3] + __bfloat162float(bg[0]);
    af[row] = 1.f / (1.f + expf(-tot));
  }
}

// ---------------- EPE rope, in-place on q_r (in qcr) and k_r (in xproj) ----------------
__global__ __launch_bounds__(256) void rope_k(bf16* __restrict__ qcr,
                                              bf16* __restrict__ xproj,
                                              const float* __restrict__ unc) {
  int idx = blockIdx.x * 256 + threadIdx.x;
  int j = idx & 31, h = (idx >> 5) & 15, bt = idx >> 9;
  int t = bt & (T_SEQ - 1);
  float u = unc[bt];
  u = fminf(fmaxf(u, 0.f), 1.f);
  float scale = 0.5f + 1.5f * u;
  float theta = expf(-(float)j * (1.f / 32.f) * logf(500000.f));
  float f = (float)t * theta * scale;
  float c = cosf(f), s = sinf(f);
  size_t base = (size_t)bt * 3072 + 2048 + h * RDIM + j;
  {
    float x1 = __bfloat162float(qcr[base]), x2 = __bfloat162float(qcr[base + 32]);
    qcr[base]      = __float2bfloat16(x1 * c - x2 * s);
    qcr[base + 32] = __float2bfloat16(x2 * c + x1 * s);
  }
  {
    float x1 = __bfloat162float(xproj[base]), x2 = __bfloat162float(xproj[base + 32]);
    xproj[base]      = __float2bfloat16(x1 * c - x2 * s);
    xproj[base + 32] = __float2bfloat16(x2 * c + x1 * s);
  }
}

// ---------------- flash attention, fixed-max softmax, DMA staging ----------------
// 512 threads = 8 waves, Q-tile 128, K-tile 64.
// K LDS: 64 keys x 24 granules(16B), slot = key*24 + (kq + 3*(key&7))%24
//   -> frag-read offset koff[s] = (s*4+quad+3*(l16&7))%24, j-independent.
// V LDS: 128 d x 8 granules, slot = d*8 + (kg+d)&7 -> voff[st]=(st*4+quad+l16)&7.
// Both give uniform 8-lane-per-bank-group distribution (same class as the
// proven padded layouts). Staging = 5 global_load_lds per wave per iter.
template <int IS_AR>
__global__ __launch_bounds__(512) void attn_k(const bf16* __restrict__ qcr,
                                              const bf16* __restrict__ kcv,
                                              const bf16* __restrict__ xproj,
                                              const bf16* __restrict__ vt,
                                              const bf16* __restrict__ ob,
                                              const float* __restrict__ alphaF,
                                              bf16* __restrict__ out) {
  constexpr int LDP = 72;
  __shared__ __align__(16) short lk[1536 * 8];    // 24.6 KB
  __shared__ __align__(16) short lvt[1024 * 8];   // 16.4 KB
  __shared__ __align__(16) short lp[8 * 16 * LDP];// 18.4 KB

  const int b = blockIdx.z, h = blockIdx.y, qt = blockIdx.x;
  const int qs = qt * 128;
  const int tid = threadIdx.x;
  const int w = tid >> 6, lane = tid & 63, quad = lane >> 4, l16 = lane & 15;
  const int q0 = qs + w * 16;

  // Q fragments (A-layout) from fused qcr buffer
  v8bf qf[6];
  {
    int qrow = q0 + l16;
    const bf16* qcb = qcr + ((size_t)b * T_SEQ + qrow) * 3072 + h * HDIM;
#pragma unroll
    for (int s_ = 0; s_ < 4; s_++)
      qf[s_] = *reinterpret_cast<const v8bf*>(qcb + s_ * 32 + quad * 8);
    const bf16* qrb = qcr + ((size_t)b * T_SEQ + qrow) * 3072 + 2048 + h * RDIM;
#pragma unroll
    for (int s_ = 0; s_ < 2; s_++)
      qf[4 + s_] = *reinterpret_cast<const v8bf*>(qrb + s_ * 32 + quad * 8);
  }

  int klo = 0, khi = T_SEQ;
  if (IS_AR) {
    int c = qs >> 8;
    klo = (c > 0) ? (c * 256 - 256) : 0;
    khi = qs + 128;
  }

  // staging decode: 40 chunks of 64 granules (24 K + 16 V), 5 per wave
  const bf16* srcp[5];
  int sstr[5];
  short* dstb[5];
#pragma unroll
  for (int i = 0; i < 5; i++) {
    int ci = w * 5 + i;
    int s = ci * 64 + lane;
    if (s < 1536) {
      int key = s / 24;
      int p = s - key * 24;
      int kq = (p + 24 - 3 * (key & 7)) % 24;
      if (kq < 16) { srcp[i] = kcv + ((size_t)b * T_SEQ + key) * 4096 + h * HDIM + kq * 8; sstr[i] = 4096; }
      else         { srcp[i] = xproj + ((size_t)b * T_SEQ + key) * 3072 + 2048 + h * RDIM + (kq - 16) * 8; sstr[i] = 3072; }
      dstb[i] = lk + ci * 512;
    } else {
      int t = s - 1536;
      int d = t >> 3, p8 = t & 7;
      int kg = (p8 + 8 - (d & 7)) & 7;
      srcp[i] = vt + (size_t)(h * HDIM + d) * (2 * T_SEQ) + b * T_SEQ + kg * 8;
      sstr[i] = 1;
      dstb[i] = lvt + (ci - 24) * 512;
    }
    srcp[i] += (size_t)klo * sstr[i];
  }

  // frag-read swizzle offsets (loop-invariant)
  int koff[6];
#pragma unroll
  for (int s_ = 0; s_ < 6; s_++) koff[s_] = (s_ * 4 + quad + 3 * (l16 & 7)) % 24;
  const int voff0 = (quad + l16) & 7;
  const int voff1 = (4 + quad + l16) & 7;

  float l_lane[4] = {0.f, 0.f, 0.f, 0.f};
  v4f oacc[8];
#pragma unroll
  for (int i = 0; i < 8; i++) oacc[i] = (v4f){0.f, 0.f, 0.f, 0.f};

  const float sc = 0.07216878364870323f;  // 1/sqrt(192)
  short* pw = &lp[w * 16 * LDP];

  for (int kb = klo; kb < khi; kb += 64) {
    __syncthreads();  // WAR on lk/lvt
#pragma unroll
    for (int i = 0; i < 5; i++) {
      gl_lds16(srcp[i], dstb[i]);
      srcp[i] += (size_t)64 * sstr[i];
    }
    __syncthreads();  // drains vmcnt(0): DMA complete

    const bool wactive = !IS_AR || (kb <= q0 + 15);
    if (wactive) {
      float pnew[4][4];
#pragma unroll
      for (int j = 0; j < 4; j++) {
        const bool jact = !IS_AR || (kb + j * 16 <= q0 + 15);
        if (jact) {
          v4f a = (v4f){0.f, 0.f, 0.f, 0.f};
#pragma unroll
          for (int s_ = 0; s_ < 6; s_++) {
            v8bf kf = *reinterpret_cast<const v8bf*>(&lk[((j * 16 + l16) * 24 + koff[s_]) * 8]);
            a = __builtin_amdgcn_mfma_f32_16x16x32_bf16(qf[s_], kf, a, 0, 0, 0);
          }
#pragma unroll
          for (int r = 0; r < 4; r++) {
            float p = __expf(a[r] * sc);
            if (IS_AR) {
              int k = kb + j * 16 + l16;
              int q = q0 + quad * 4 + r;
              p = (k <= q) ? p : 0.f;
            }
            pnew[r][j] = p;
            l_lane[r] += p;
          }
        } else {
#pragma unroll
          for (int r = 0; r < 4; r++) pnew[r][j] = 0.f;
        }
      }
      // P: C-layout -> wave-private LDS -> A-layout
#pragma unroll
      for (int r = 0; r < 4; r++) {
        int prow = quad * 4 + r;
#pragma unroll
        for (int j = 0; j < 4; j++)
          pw[prow * LDP + j * 16 + l16] = f2bfbits(pnew[r][j]);
      }
      asm volatile("s_waitcnt lgkmcnt(0)" ::: "memory");
      v8bf pf[2];
#pragma unroll
      for (int st = 0; st < 2; st++)
        pf[st] = *reinterpret_cast<const v8bf*>(&pw[l16 * LDP + st * 32 + quad * 8]);
#pragma unroll
      for (int nd = 0; nd < 8; nd++) {
        {
          v8bf vf = *reinterpret_cast<const v8bf*>(&lvt[((nd * 16 + l16) * 8 + voff0) * 8]);
          oacc[nd] = __builtin_amdgcn_mfma_f32_16x16x32_bf16(pf[0], vf, oacc[nd], 0, 0, 0);
        }
        {
          v8bf vf = *reinterpret_cast<const v8bf*>(&lvt[((nd * 16 + l16) * 8 + voff1) * 8]);
          oacc[nd] = __builtin_amdgcn_mfma_f32_16x16x32_bf16(pf[1], vf, oacc[nd], 0, 0, 0);
        }
      }
    }
  }

  // epilogue
#pragma unroll
  for (int r = 0; r < 4; r++) {
    float l = l_lane[r];
#pragma unroll
    for (int m = 1; m < 16; m <<= 1) l += __shfl_xor(l, m);
    float inv = 1.f / l;
    int q = q0 + quad * 4 + r;
    size_t base = ((size_t)b * T_SEQ + q) * DMODEL + h * HDIM;
    if (IS_AR) {
      float a = alphaF[b * T_SEQ + q];
#pragma unroll
      for (int nd = 0; nd < 8; nd++) {
        float vb = __bfloat162float(ob[base + nd * 16 + l16]);
        out[base + nd * 16 + l16] = __float2bfloat16(a * vb + (1.f - a) * (oacc[nd][r] * inv));
      }
    } else {
#pragma unroll
      for (int nd = 0; nd < 8; nd++)
        out[base + nd * 16 + l16] = __float2bfloat16(oacc[nd][r] * inv);
    }
  }
}

// ---------------- emit: fp32 staging -> d_out in detected dtype ----------------
__global__ __launch_bounds__(256) void emit_k(const float* __restrict__ outf,
                                              const float* __restrict__ alphaF,
                                              void* __restrict__ dout,
                                              const int* __restrict__ flag) {
  int idx = blockIdx.x * 256 + threadIdx.x;
  float vv = (idx < 8388608) ? outf[idx] : alphaF[idx - 8388608];
  if (*flag) ((float*)dout)[idx] = vv;
  else       ((bf16*)dout)[idx] = __float2bfloat16(vv);
}

extern "C" void kernel_launch(void* const* d_in, const int* in_sizes, int n_in,
                              void* d_out, int out_size, void* d_ws, size_t ws_size,
                              hipStream_t stream) {
  const void* x_raw    = d_in[0];
  const void* unc_raw  = d_in[1];
  const void* Wqd_raw  = d_in[2];
  const void* qnw_raw  = d_in[3];
  const void* Wqu_raw  = d_in[4];
  const void* Wqr_raw  = d_in[5];
  const void* Wkvd_raw = d_in[6];
  const void* kvnw_raw = d_in[7];
  const void* Wku_raw  = d_in[8];
  const void* Wvu_raw  = d_in[9];
  const void* Wkr_raw  = d_in[10];
  const void* Wo_raw   = d_in[11];
  const void* Wg_raw   = d_in[12];
  const void* bg_raw   = d_in[13];

  char* ws = (char*)d_ws;
  size_t off = 0;
  auto alloc = [&](size_t bytes) -> void* {
    char* p = ws + off;
    off += (bytes + 255) & ~(size_t)255;
    return p;
  };
  int*  flag   = (int*)alloc(256);
  bf16* xc     = (bf16*)alloc((size_t)4096 * 2048 * 2);
  float* uncf  = (float*)alloc((size_t)4096 * 4);
  bf16* qnw    = (bf16*)alloc(1536 * 2);
  bf16* kvnw   = (bf16*)alloc(512 * 2);
  bf16* wgc    = (bf16*)alloc(2048 * 2);
  bf16* bgc    = (bf16*)alloc(256);
  // fused transposed-weight buffers
  bf16* BT1    = (bf16*)alloc((size_t)3072 * 2048 * 2);  // [WqdT;WkvdT;WkrT], K=2048
  bf16* BT2    = (bf16*)alloc((size_t)3072 * 1536 * 2);  // [WquT;WqrT], K=1536
  bf16* BT3    = (bf16*)alloc((size_t)4096 * 512 * 2);   // [WkuT;WvuT], K=512
  bf16* WoT    = (bf16*)alloc((size_t)2048 * 2048 * 2);
  // activations
  bf16* xproj  = (bf16*)alloc((size_t)4096 * 3072 * 2);  // [q_raw|kv_raw|k_r]
  bf16* q_lat  = (bf16*)alloc((size_t)4096 * 1536 * 2);
  bf16* kv_lat = (bf16*)alloc((size_t)4096 * 512 * 2);
  bf16* qcr    = (bf16*)alloc((size_t)4096 * 3072 * 2);  // [q_c|q_r]
  bf16* kcv    = (bf16*)alloc((size_t)4096 * 4096 * 2);  // [k_c|v]; reused as out_f
  bf16* vT     = (bf16*)alloc((size_t)4096 * 2048 * 2);
  bf16* out_b  = (bf16*)alloc((size_t)4096 * 2048 * 2);
  bf16* merged = (bf16*)alloc((size_t)4096 * 2048 * 2);
  float* alphaF= (float*)alloc((size_t)4096 * 4);
  float* out_f = (float*)kcv;  // kcv (33.6 MB) dead after attn; final GEMM output fp32

  detect_k<<<1, 256, 0, stream>>>((const unsigned*)x_raw, flag);

  conv_bf_k<<<32768, 256, 0, stream>>>(x_raw, xc, flag, 4096 * 2048);
  conv_small<<<33, 256, 0, stream>>>(qnw_raw, kvnw_raw, Wg_raw, bg_raw, unc_raw,
                                     qnw, kvnw, wgc, bgc, uncf, flag);

  auto lt = [&](const void* s, bf16* d, int r, int c) {
    transpose_any<<<dim3(c / 32, r / 32), 256, 0, stream>>>(s, d, r, c, flag);
  };
  lt(Wqd_raw,  BT1,                      2048, 1536);
  lt(Wkvd_raw, BT1 + (size_t)1536 * 2048, 2048, 512);
  lt(Wkr_raw,  BT1 + (size_t)2048 * 2048, 2048, 1024);
  lt(Wqu_raw,  BT2,                      1536, 2048);
  lt(Wqr_raw,  BT2 + (size_t)2048 * 1536, 1536, 1024);
  lt(Wku_raw,  BT3,                      512, 2048);
  lt(Wvu_raw,  BT3 + (size_t)2048 * 512,  512, 2048);
  lt(Wo_raw,   WoT,                      2048, 2048);

  auto gemmf = [&](const bf16* A, const bf16* BT, float* C, int M, int N, int K) {
    gemm_tn<<<dim3(N / 128, M / 128), 256, 0, stream>>>(A, BT, C, nullptr, M, N, K);
  };
  auto gemmb = [&](const bf16* A, const bf16* BT, bf16* C, int M, int N, int K) {
    gemm_tn<<<dim3(N / 128, M / 128), 256, 0, stream>>>(A, BT, nullptr, C, M, N, K);
  };

  // fused projections
  gemmb(xc, BT1, xproj, 4096, 3072, 2048);                 // [q_raw|kv_raw|k_r]
  rmsnorm_k<<<4096, 256, 0, stream>>>(xproj, 3072, 0,    qnw,  q_lat,  1536);
  rmsnorm_k<<<4096, 256, 0, stream>>>(xproj, 3072, 1536, kvnw, kv_lat, 512);
  gemmb(q_lat, BT2, qcr, 4096, 3072, 1536);                // [q_c|q_r]
  gemmb(kv_lat, BT3, kcv, 4096, 4096, 512);                // [k_c|v]

  // V^T: vT[d][b*T+t] from kcv cols 2048..4095
  transpose_str<<<dim3(64, 128), 256, 0, stream>>>(kcv + 2048, vT, 4096, 4096);

  rope_k<<<8192, 256, 0, stream>>>(qcr, xproj, uncf);
  gate_k<<<4096, 256, 0, stream>>>(xc, wgc, bgc, alphaF);

  attn_k<0><<<dim3(16, 16, 2), 512, 0, stream>>>(qcr, kcv, xproj, vT, nullptr, nullptr, out_b);
  attn_k<1><<<dim3(16, 16, 2), 512, 0, stream>>>(qcr, kcv, xproj, vT, out_b, alphaF, merged);

  gemmf(merged, WoT, out_f, 4096, 2048, 2048);
  emit_k<<<32784, 256, 0, stream>>>(out_f, alphaF, d_out, flag);

  (void)in_sizes; (void)n_in; (void)out_size; (void)ws_size;
}